// Round 8
// baseline (1034.758 us; speedup 1.0000x reference)
//
#include <hip/hip_runtime.h>
#include <math.h>

#define TT 200
#define CHN 256
#define FEAT 2048
#define DUR 64
#define RESN 16

// ---------------- base conv1d partial: 16oc x 64t tile over 256-c slice ----------------
__global__ __launch_bounds__(256, 4)
void base_conv_part(const float* __restrict__ x, const float* __restrict__ w,
                    float* __restrict__ partial) {
  __shared__ float xt[16*68];
  __shared__ float wl[16*16*4];
  int tid = threadIdx.x;
  int tl = tid & 63, wg = tid >> 6;
  int t0 = blockIdx.x * 64;
  int ocg = blockIdx.y;
  int cs = blockIdx.z >> 1, b = blockIdx.z & 1;
  const float* xb = x + (size_t)b * FEAT * TT;
  float acc[4] = {0.f, 0.f, 0.f, 0.f};

  for (int ch = 0; ch < 16; ++ch) {
    int c0 = cs * 256 + ch * 16;
    __syncthreads();
    for (int idx = tid; idx < 16*68; idx += 256) {
      int ic = idx / 68, col = idx - ic*68;
      int gt = t0 + col - 1;
      float v = 0.f;
      if (col < 66 && (unsigned)gt < (unsigned)TT) v = xb[(c0+ic)*TT + gt];
      xt[idx] = v;
    }
    for (int idx = tid; idx < 16*16*3; idx += 256) {
      int oc = idx / 48, rem = idx - oc*48;
      int ic = rem / 3, kk = rem - ic*3;
      wl[(oc*16 + ic)*4 + kk] = w[((ocg*16+oc)*FEAT + c0+ic)*3 + kk];
    }
    __syncthreads();
    #pragma unroll
    for (int ic = 0; ic < 16; ++ic) {
      float v0 = xt[ic*68 + tl];
      float v1 = xt[ic*68 + tl + 1];
      float v2 = xt[ic*68 + tl + 2];
      #pragma unroll
      for (int j = 0; j < 4; ++j) {
        const float4 wv = *(const float4*)(wl + ((wg*4+j)*16 + ic)*4);
        acc[j] += wv.x*v0 + wv.y*v1 + wv.z*v2;
      }
    }
  }
  int t = t0 + tl;
  if (t < TT) {
    #pragma unroll
    for (int j = 0; j < 4; ++j) {
      int oc = ocg*16 + wg*4 + j;
      partial[((cs*2 + b)*CHN + oc)*TT + t] = acc[j];
    }
  }
}

__global__ void base_reduce(const float* __restrict__ partial, const float* __restrict__ bias,
                            float* __restrict__ h) {
  int idx = blockIdx.x * 256 + threadIdx.x;
  if (idx >= 2*CHN*TT) return;
  int b = idx / (CHN*TT);
  int rem = idx - b*CHN*TT;
  int o = rem / TT;
  float s = bias[o];
  #pragma unroll
  for (int cs = 0; cs < 8; ++cs) s += partial[(cs*2 + b)*CHN*TT + rem];
  h[idx] = fmaxf(s, 0.f);
}

// ---------------- fused q/k/v projection (multi-slot via blockIdx.z) ----------------
__global__ void qkv_kernel(const float* __restrict__ Wq_base, const float* __restrict__ Wk_base,
                           const float* __restrict__ Wv_base, int slot0,
                           const float* __restrict__ in,
                           float* __restrict__ q, float* __restrict__ k, float* __restrict__ v) {
  int t = blockIdx.x * 64 + threadIdx.x;
  int o = blockIdx.y;
  int z = blockIdx.z;
  int si = z >> 1, b = z & 1;
  if (t >= TT) return;
  const float* inb = in + b * CHN * TT;
  const float* wqr = Wq_base + (slot0+si)*CHN*CHN + o*CHN;
  const float* wkr = Wk_base + (slot0+si)*CHN*CHN + o*CHN;
  const float* wvr = Wv_base + (slot0+si)*CHN*CHN + o*CHN;
  float aq0 = 0.f, ak0 = 0.f, av0 = 0.f;
  float aq1 = 0.f, ak1 = 0.f, av1 = 0.f;
  #pragma unroll 4
  for (int c = 0; c < 128; ++c) {
    float x0 = inb[c*TT + t];
    float x1 = inb[(c+128)*TT + t];
    aq0 += wqr[c] * x0;      aq1 += wqr[c+128] * x1;
    ak0 += wkr[c] * x0;      ak1 += wkr[c+128] * x1;
    av0 += wvr[c] * x0;      av1 += wvr[c+128] * x1;
  }
  int off = si*CHN*TT*2 + (b*CHN + o)*TT + t;
  q[off] = aq0 + aq1;
  k[off] = ak0 + ak1;
  v[off] = av0 + av1;
}

// ---------------- output projection: out = relu(W @ in) + resid (multi-slot) ----------------
__global__ void proj_kernel(const float* __restrict__ Wo_base, int slot0,
                            const float* __restrict__ in, const float* __restrict__ resid,
                            float* __restrict__ outb) {
  int t = blockIdx.x * 64 + threadIdx.x;
  int o = blockIdx.y;
  int z = blockIdx.z;
  int si = z >> 1, b = z & 1;
  if (t >= TT) return;
  const float* wrow = Wo_base + (slot0+si)*CHN*CHN + o*CHN;
  const float* inb = in + si*CHN*TT*2 + b*CHN*TT;
  float a0 = 0.f, a1 = 0.f, a2 = 0.f, a3 = 0.f;
  #pragma unroll 4
  for (int c = 0; c < 64; ++c) {
    a0 += wrow[c]     * inb[c*TT + t];
    a1 += wrow[c+64]  * inb[(c+64)*TT + t];
    a2 += wrow[c+128] * inb[(c+128)*TT + t];
    a3 += wrow[c+192] * inb[(c+192)*TT + t];
  }
  float acc = (a0 + a1) + (a2 + a3);
  acc = fmaxf(acc, 0.f) + resid[(b*CHN + o)*TT + t];
  outb[si*CHN*TT*2 + (b*CHN + o)*TT + t] = acc;
}

// ---------------- banded attention (multi-slot) ----------------
__global__ void attn_kernel(const float* __restrict__ q, const float* __restrict__ k,
                            const float* __restrict__ v, const float* __restrict__ pos,
                            float* __restrict__ Aout_base, long long Astride,
                            float* __restrict__ out) {
  int t = blockIdx.x;
  int z = blockIdx.y;
  int si = z >> 1, b = z & 1;
  int lane = threadIdx.x;  // 64
  const float* qb = q + si*CHN*TT*2 + b * CHN * TT;
  const float* kb = k + si*CHN*TT*2 + b * CHN * TT;
  const float* vb = v + si*CHN*TT*2 + b * CHN * TT;
  float qc[4];
  #pragma unroll
  for (int i = 0; i < 4; ++i) qc[i] = qb[(lane + 64*i)*TT + t];

  float sc[17];
  #pragma unroll
  for (int j = 0; j < 17; ++j) {
    int s = t - 8 + j;
    bool inr = (s >= 0) && (s < TT);
    int ss = s < 0 ? 0 : (s > TT-1 ? TT-1 : s);
    float p = 0.f;
    #pragma unroll
    for (int i = 0; i < 4; ++i) p += qc[i] * kb[(lane + 64*i)*TT + ss];
    #pragma unroll
    for (int off = 32; off > 0; off >>= 1) p += __shfl_xor(p, off, 64);
    sc[j] = inr ? (p * 0.0625f + pos[t*TT + ss]) : -3.0e38f;
  }
  float m8 = sc[0];
  #pragma unroll
  for (int j = 1; j < 17; ++j) m8 = fmaxf(m8, sc[j]);
  float m4 = sc[4];
  #pragma unroll
  for (int j = 5; j < 13; ++j) m4 = fmaxf(m4, sc[j]);
  float e8[17], s8 = 0.f;
  #pragma unroll
  for (int j = 0; j < 17; ++j) { e8[j] = expf(sc[j] - m8); s8 += e8[j]; }
  float e4[9], s4 = 0.f;
  #pragma unroll
  for (int j = 0; j < 9; ++j) { e4[j] = expf(sc[4+j] - m4); s4 += e4[j]; }
  float i8 = 1.f / s8, i4 = 1.f / s4;
  float asum[17];
  #pragma unroll
  for (int j = 0; j < 17; ++j) {
    float a = e8[j] * i8;
    if (j >= 4 && j <= 12) a += e4[j-4] * i4;
    asum[j] = a;
  }
  #pragma unroll
  for (int i = 0; i < 4; ++i) {
    float acc = 0.f;
    #pragma unroll
    for (int j = 0; j < 17; ++j) {
      int s = t - 8 + j;
      int ss = s < 0 ? 0 : (s > TT-1 ? TT-1 : s);
      acc += asum[j] * vb[(lane + 64*i)*TT + ss];
    }
    out[si*CHN*TT*2 + (b*CHN + lane + 64*i)*TT + t] = acc;
  }
  __shared__ float lds_a[17];
  #pragma unroll
  for (int j = 0; j < 17; ++j) if (lane == j) lds_a[j] = asum[j];
  __syncthreads();
  float* Aout = Aout_base + (long long)si * Astride;
  for (int s = lane; s < TT; s += 64) {
    int j = s - (t - 8);
    float a = (j >= 0 && j < 17) ? lds_a[j] : 0.f;
    Aout[(b*TT + t)*TT + s] = a;
  }
}

// ---------------- start/end head ----------------
__global__ void head_kernel(const float* __restrict__ feat, const float* __restrict__ w,
                            const float* __restrict__ bias, float* __restrict__ outp) {
  int t = blockIdx.x * 64 + threadIdx.x;
  int b = blockIdx.y;
  if (t >= TT) return;
  float acc = bias[0];
  #pragma unroll 8
  for (int c = 0; c < CHN; ++c) acc += w[c] * feat[(b*CHN + c)*TT + t];
  outp[b*TT + t] = 1.f / (1.f + expf(-acc));
}

// ---------------- transpose cw1 into wT[r][c][o] ----------------
__global__ void w1t_kernel(const float* __restrict__ cw1, float* __restrict__ wT) {
  int idx = blockIdx.x * 256 + threadIdx.x;
  if (idx >= 128 * 4096) return;
  int o = idx >> 12;
  int cr = idx & 4095;
  int c = cr >> 4;
  int r = cr & 15;
  wT[(r*CHN + c)*128 + o] = cw1[idx];
}

// ---------------- g[b][r][x][o] = sum_c wT[r][c][o] * cfeat[b][c][x] ----------------
__global__ void g_kernel(const float* __restrict__ wT, const float* __restrict__ cf,
                         float* __restrict__ g) {
  int o = threadIdx.x;      // 128
  int xt = blockIdx.x;      // 50 tiles of 4
  int r = blockIdx.y;       // 16
  int b = blockIdx.z;       // 2
  float acc[4] = {0.f, 0.f, 0.f, 0.f};
  const float* wp = wT + r*CHN*128 + o;
  const float* cp = cf + b*CHN*TT + xt*4;
  for (int c = 0; c < CHN; ++c) {
    float wv = wp[c*128];
    #pragma unroll
    for (int j = 0; j < 4; ++j) acc[j] += wv * cp[c*TT + j];
  }
  float* gp = g + ((b*RESN + r)*TT + xt*4)*128 + o;
  #pragma unroll
  for (int j = 0; j < 4; ++j) gp[j*128] = acc[j];
}

// ---------------- fused align + 1x1 conv (cw1) + relu -> y1[b][o][d][t] ----------------
__global__ void align_conv1_kernel(const float* __restrict__ g, const float* __restrict__ cb1,
                                   float* __restrict__ y1) {
  int o = threadIdx.x;      // 128
  int t = blockIdx.x;       // 200
  int d = blockIdx.y;       // 64
  int b = blockIdx.z;
  bool vanch = (t + d) < TT;
  float clen = d + 1.0f;
  float xmin = vanch ? (t - clen * 0.5f) : 0.f;
  float xmax = vanch ? (t + d + clen * 0.5f) : 0.f;
  float acc = cb1[o];
  const float* gb = g + b*RESN*TT*128;
  #pragma unroll
  for (int r = 0; r < RESN; ++r) {
    float frac = (r + 0.5f) * (1.f/16.f);
    float p = xmin + (xmax - xmin) * frac;
    float x0 = floorf(p);
    float wf = p - x0;
    int x0i = (int)fminf(fmaxf(x0, 0.f), (float)(TT-1));
    int x1i = (int)fminf(fmaxf(x0 + 1.f, 0.f), (float)(TT-1));
    bool vp = (p >= -1.0f) && (p <= (float)TT);
    if (vp) {
      const float* gr = gb + r*TT*128;
      acc += (1.f - wf) * gr[x0i*128 + o] + wf * gr[x1i*128 + o];
    }
  }
  y1[((b*128 + o)*DUR + d)*TT + t] = fmaxf(acc, 0.f);
}

// ---------------- weight pre-pack for conv3x3 v3 ----------------
// src [oc(128)][ic(128)][9] -> dst [ocg(4)][wg(4)][blk(16)][icl(8)][j(8)][9]
__global__ void wpack_kernel(const float* __restrict__ cw2, const float* __restrict__ cw3,
                             float* __restrict__ dst) {
  int z = blockIdx.y;
  const float* src = z ? cw3 : cw2;
  float* d = dst + z*147456;
  int idx = blockIdx.x*256 + threadIdx.x;
  if (idx >= 147456) return;
  int k = idx % 9;
  int rem = idx / 9;     // oc*128+ic
  int ic = rem & 127;
  int oc = rem >> 7;
  int ocg = oc >> 5, ocl = oc & 31, wg = ocl >> 3, j = ocl & 7;
  int blk = ic >> 3, icl = ic & 7;
  d[((((ocg*4 + wg)*16 + blk)*8 + icl)*8 + j)*9 + k] = src[idx];
}

// ---------------- 3x3 conv v3: 8oc x 4d per thread, packed scalar weights ----------------
// Block 256 = 4 waves; output tile 32 oc x 4 d x 64 t; grid (4, 16, b*4+ocg) = 512.
__global__ __launch_bounds__(256, 2)
void conv3x3_kernel(const float* __restrict__ in, const float* __restrict__ wpk,
                    const float* __restrict__ bias, float* __restrict__ out) {
  __shared__ float tile[2][6*8*68];
  int tid = threadIdx.x;
  int tl = tid & 63;
  int wg = tid >> 6;
  int t0 = blockIdx.x * 64;
  int d0 = blockIdx.y * 4;
  int z = blockIdx.z;
  int b = z >> 2;
  int ocg = z & 3;
  const float* inb = in + (size_t)b*128*DUR*TT;
  int wgu = __builtin_amdgcn_readfirstlane(wg);
  const float* wwave = wpk + (size_t)(ocg*4 + wgu)*9216;   // 16*8*72

  float acc[4][8];
  #pragma unroll
  for (int dd = 0; dd < 4; ++dd)
    #pragma unroll
    for (int j = 0; j < 8; ++j) acc[dd][j] = 0.f;

  int gt = t0 + tl - 1;
  bool tok0 = (unsigned)gt < (unsigned)TT;
  bool tok1 = (tl < 4) && ((unsigned)(gt+64) < (unsigned)TT);

  #define C3_STAGE(BUF, IC0)                                                     \
    {                                                                            \
      _Pragma("unroll")                                                          \
      for (int p = 0; p < 12; ++p) {                                             \
        int pair = p*4 + wg;                                                     \
        int row = pair >> 3, ic = pair & 7;                                      \
        int gd = d0 + row - 1;                                                   \
        bool dok = (unsigned)gd < (unsigned)DUR;                                 \
        const float* src = inb + ((IC0)+ic)*DUR*TT + gd*TT + gt;                 \
        float v0 = (dok && tok0) ? src[0] : 0.f;                                 \
        tile[BUF][pair*68 + tl] = v0;                                            \
        if (tl < 4) {                                                            \
          float v1 = (dok && tok1) ? src[64] : 0.f;                              \
          tile[BUF][pair*68 + tl + 64] = v1;                                     \
        }                                                                        \
      }                                                                          \
    }

  C3_STAGE(0, 0)
  __syncthreads();
  int buf = 0;
  for (int blk = 0; blk < 16; ++blk) {
    if (blk < 15) {
      if (buf == 0) C3_STAGE(1, (blk+1)*8)
      else          C3_STAGE(0, (blk+1)*8)
    }
    #pragma unroll 2
    for (int ic = 0; ic < 8; ++ic) {
      float vv[6][3];
      #pragma unroll
      for (int r = 0; r < 6; ++r)
        #pragma unroll
        for (int c2 = 0; c2 < 3; ++c2)
          vv[r][c2] = tile[buf][(r*8+ic)*68 + tl + c2];
      const float* wic = wwave + (blk*8 + ic)*72;
      #pragma unroll
      for (int j = 0; j < 8; ++j) {
        const float* wj = wic + j*9;
        float w0=wj[0], w1=wj[1], w2=wj[2], w3=wj[3], w4=wj[4],
              w5=wj[5], w6=wj[6], w7=wj[7], w8=wj[8];
        #pragma unroll
        for (int dd = 0; dd < 4; ++dd) {
          float s = acc[dd][j];
          s += w0*vv[dd][0]   + w1*vv[dd][1]   + w2*vv[dd][2];
          s += w3*vv[dd+1][0] + w4*vv[dd+1][1] + w5*vv[dd+1][2];
          s += w6*vv[dd+2][0] + w7*vv[dd+2][1] + w8*vv[dd+2][2];
          acc[dd][j] = s;
        }
      }
    }
    __syncthreads();
    buf ^= 1;
  }
  #undef C3_STAGE

  int t = t0 + tl;
  if (t < TT) {
    #pragma unroll
    for (int j = 0; j < 8; ++j) {
      int oc = ocg*32 + wgu*8 + j;
      float bv = bias[oc];
      #pragma unroll
      for (int dd = 0; dd < 4; ++dd)
        out[((b*128+oc)*DUR + d0+dd)*TT + t] = fmaxf(acc[dd][j] + bv, 0.f);
    }
  }
}

// ---------------- final 1x1 conv 128->2 + sigmoid -> conf ----------------
__global__ void conv4_kernel(const float* __restrict__ in, const float* __restrict__ w,
                             const float* __restrict__ bias, float* __restrict__ conf) {
  int t = blockIdx.x * 64 + threadIdx.x;
  int d = blockIdx.y;
  int b = blockIdx.z;
  if (t >= TT) return;
  float a0 = bias[0], a1 = bias[1];
  #pragma unroll 4
  for (int i = 0; i < 128; ++i) {
    float vv = in[((b*128 + i)*DUR + d)*TT + t];
    a0 += w[i] * vv;
    a1 += w[128 + i] * vv;
  }
  conf[((b*2 + 0)*DUR + d)*TT + t] = 1.f / (1.f + expf(-a0));
  conf[((b*2 + 1)*DUR + d)*TT + t] = 1.f / (1.f + expf(-a1));
}

extern "C" void kernel_launch(void* const* d_in, const int* in_sizes, int n_in,
                              void* d_out, int out_size, void* d_ws, size_t ws_size,
                              hipStream_t stream) {
  const float* x       = (const float*)d_in[0];
  const float* base_w  = (const float*)d_in[1];
  const float* base_b  = (const float*)d_in[2];
  const float* wq      = (const float*)d_in[3];
  const float* wk      = (const float*)d_in[4];
  const float* wv      = (const float*)d_in[5];
  const float* wo      = (const float*)d_in[6];
  const float* pos     = (const float*)d_in[7];
  const float* start_w = (const float*)d_in[8];
  const float* start_b = (const float*)d_in[9];
  const float* end_w   = (const float*)d_in[10];
  const float* end_b   = (const float*)d_in[11];
  const float* cw1     = (const float*)d_in[12];
  const float* cb1     = (const float*)d_in[13];
  const float* cw2     = (const float*)d_in[14];
  const float* cb2     = (const float*)d_in[15];
  const float* cw3     = (const float*)d_in[16];
  const float* cb3     = (const float*)d_in[17];
  const float* cw4     = (const float*)d_in[18];
  const float* cb4     = (const float*)d_in[19];

  float* out = (float*)d_out;
  float* conf_out  = out;
  float* start_out = out + 51200;
  float* end_out   = out + 51600;
  float* As_out    = out + 52000;    // Ae, Ap follow at stride 80000

  float* ws = (float*)d_ws;
  float* h      = ws;                 // 102400
  float* basef  = ws + 102400;        // 102400
  float* feats3 = ws + 204800;        // 307200
  float* wT     = ws + 512000;        // 524288 (reused for packed conv weights after g_kernel)
  float* gbuf   = ws + 1036288;       // 819200
  float* y1     = ws + 1855488;       // 3276800
  float* y2     = ws + 5132288;       // 3276800
  float* qb3    = y1;                 // overlays in y1
  float* kb3    = y1 + 307200;
  float* vb3    = y1 + 614400;
  float* ao3    = y1 + 921600;
  float* partial= y1 + 1228800;
  float* A_scr  = y2;                 // overlay in y2 (write-only G, dead after)
  float* wpk    = wT;                 // overlay in wT region (294912 <= 524288), after g_kernel

  dim3 b64(64);
  dim3 b256(256);

  base_conv_part<<<dim3(4, 16, 16), b256, 0, stream>>>(x, base_w, partial);
  base_reduce<<<dim3(400), b256, 0, stream>>>(partial, base_b, h);

  qkv_kernel<<<dim3(4, 256, 2), b64, 0, stream>>>(wq, wk, wv, 0, h, qb3, kb3, vb3);
  attn_kernel<<<dim3(200, 2), b64, 0, stream>>>(qb3, kb3, vb3, pos, A_scr, 0, ao3);
  proj_kernel<<<dim3(4, 256, 2), b64, 0, stream>>>(wo, 0, ao3, h, basef);

  qkv_kernel<<<dim3(4, 256, 6), b64, 0, stream>>>(wq, wk, wv, 1, basef, qb3, kb3, vb3);
  attn_kernel<<<dim3(200, 6), b64, 0, stream>>>(qb3, kb3, vb3, pos, As_out, 80000, ao3);
  proj_kernel<<<dim3(4, 256, 6), b64, 0, stream>>>(wo, 1, ao3, basef, feats3);

  head_kernel<<<dim3(4, 2), b64, 0, stream>>>(feats3, start_w, start_b, start_out);
  head_kernel<<<dim3(4, 2), b64, 0, stream>>>(feats3 + 102400, end_w, end_b, end_out);

  const float* cfeat = feats3 + 204800;
  w1t_kernel<<<dim3(2048), b256, 0, stream>>>(cw1, wT);
  g_kernel<<<dim3(50, 16, 2), dim3(128), 0, stream>>>(wT, cfeat, gbuf);
  // wT dead after g_kernel; pack conv weights into its region
  wpack_kernel<<<dim3(576, 2), b256, 0, stream>>>(cw2, cw3, wpk);
  align_conv1_kernel<<<dim3(200, 64, 2), dim3(128), 0, stream>>>(gbuf, cb1, y1);

  conv3x3_kernel<<<dim3(4, 16, 8), b256, 0, stream>>>(y1, wpk, cb2, y2);
  conv3x3_kernel<<<dim3(4, 16, 8), b256, 0, stream>>>(y2, wpk + 147456, cb3, y1);
  conv4_kernel<<<dim3(4, 64, 2), b64, 0, stream>>>(y1, cw4, cb4, conf_out);
}

// Round 12
// 648.372 us; speedup vs baseline: 1.5959x; 1.5959x over previous
//
#include <hip/hip_runtime.h>
#include <math.h>

#define TT 200
#define CHN 256
#define FEAT 2048
#define DUR 64
#define RESN 16

typedef __attribute__((ext_vector_type(8))) short short8;
typedef __attribute__((ext_vector_type(4))) float f32x4;

__device__ __forceinline__ unsigned rne_bf16(float x) {
  unsigned u = __float_as_uint(x);
  return (u + 0x7fffu + ((u >> 16) & 1u)) >> 16;
}

// ---------------- base conv1d partial: 16oc x 64t tile over 256-c slice ----------------
__global__ __launch_bounds__(256, 4)
void base_conv_part(const float* __restrict__ x, const float* __restrict__ w,
                    float* __restrict__ partial) {
  __shared__ float xt[16*68];
  __shared__ float wl[16*16*4];
  int tid = threadIdx.x;
  int tl = tid & 63, wg = tid >> 6;
  int t0 = blockIdx.x * 64;
  int ocg = blockIdx.y;
  int cs = blockIdx.z >> 1, b = blockIdx.z & 1;
  const float* xb = x + (size_t)b * FEAT * TT;
  float acc[4] = {0.f, 0.f, 0.f, 0.f};

  for (int ch = 0; ch < 16; ++ch) {
    int c0 = cs * 256 + ch * 16;
    __syncthreads();
    for (int idx = tid; idx < 16*68; idx += 256) {
      int ic = idx / 68, col = idx - ic*68;
      int gt = t0 + col - 1;
      float v = 0.f;
      if (col < 66 && (unsigned)gt < (unsigned)TT) v = xb[(c0+ic)*TT + gt];
      xt[idx] = v;
    }
    for (int idx = tid; idx < 16*16*3; idx += 256) {
      int oc = idx / 48, rem = idx - oc*48;
      int ic = rem / 3, kk = rem - ic*3;
      wl[(oc*16 + ic)*4 + kk] = w[((ocg*16+oc)*FEAT + c0+ic)*3 + kk];
    }
    __syncthreads();
    #pragma unroll
    for (int ic = 0; ic < 16; ++ic) {
      float v0 = xt[ic*68 + tl];
      float v1 = xt[ic*68 + tl + 1];
      float v2 = xt[ic*68 + tl + 2];
      #pragma unroll
      for (int j = 0; j < 4; ++j) {
        const float4 wv = *(const float4*)(wl + ((wg*4+j)*16 + ic)*4);
        acc[j] += wv.x*v0 + wv.y*v1 + wv.z*v2;
      }
    }
  }
  int t = t0 + tl;
  if (t < TT) {
    #pragma unroll
    for (int j = 0; j < 4; ++j) {
      int oc = ocg*16 + wg*4 + j;
      partial[((cs*2 + b)*CHN + oc)*TT + t] = acc[j];
    }
  }
}

__global__ void base_reduce(const float* __restrict__ partial, const float* __restrict__ bias,
                            float* __restrict__ h) {
  int idx = blockIdx.x * 256 + threadIdx.x;
  if (idx >= 2*CHN*TT) return;
  int b = idx / (CHN*TT);
  int rem = idx - b*CHN*TT;
  int o = rem / TT;
  float s = bias[o];
  #pragma unroll
  for (int cs = 0; cs < 8; ++cs) s += partial[(cs*2 + b)*CHN*TT + rem];
  h[idx] = fmaxf(s, 0.f);
}

// ---------------- fused q/k/v projection (multi-slot via blockIdx.z) ----------------
__global__ void qkv_kernel(const float* __restrict__ Wq_base, const float* __restrict__ Wk_base,
                           const float* __restrict__ Wv_base, int slot0,
                           const float* __restrict__ in,
                           float* __restrict__ q, float* __restrict__ k, float* __restrict__ v) {
  int t = blockIdx.x * 64 + threadIdx.x;
  int o = blockIdx.y;
  int z = blockIdx.z;
  int si = z >> 1, b = z & 1;
  if (t >= TT) return;
  const float* inb = in + b * CHN * TT;
  const float* wqr = Wq_base + (slot0+si)*CHN*CHN + o*CHN;
  const float* wkr = Wk_base + (slot0+si)*CHN*CHN + o*CHN;
  const float* wvr = Wv_base + (slot0+si)*CHN*CHN + o*CHN;
  float aq0 = 0.f, ak0 = 0.f, av0 = 0.f;
  float aq1 = 0.f, ak1 = 0.f, av1 = 0.f;
  #pragma unroll 4
  for (int c = 0; c < 128; ++c) {
    float x0 = inb[c*TT + t];
    float x1 = inb[(c+128)*TT + t];
    aq0 += wqr[c] * x0;      aq1 += wqr[c+128] * x1;
    ak0 += wkr[c] * x0;      ak1 += wkr[c+128] * x1;
    av0 += wvr[c] * x0;      av1 += wvr[c+128] * x1;
  }
  int off = si*CHN*TT*2 + (b*CHN + o)*TT + t;
  q[off] = aq0 + aq1;
  k[off] = ak0 + ak1;
  v[off] = av0 + av1;
}

// ---------------- output projection: out = relu(W @ in) + resid (multi-slot) ----------------
__global__ void proj_kernel(const float* __restrict__ Wo_base, int slot0,
                            const float* __restrict__ in, const float* __restrict__ resid,
                            float* __restrict__ outb) {
  int t = blockIdx.x * 64 + threadIdx.x;
  int o = blockIdx.y;
  int z = blockIdx.z;
  int si = z >> 1, b = z & 1;
  if (t >= TT) return;
  const float* wrow = Wo_base + (slot0+si)*CHN*CHN + o*CHN;
  const float* inb = in + si*CHN*TT*2 + b*CHN*TT;
  float a0 = 0.f, a1 = 0.f, a2 = 0.f, a3 = 0.f;
  #pragma unroll 4
  for (int c = 0; c < 64; ++c) {
    a0 += wrow[c]     * inb[c*TT + t];
    a1 += wrow[c+64]  * inb[(c+64)*TT + t];
    a2 += wrow[c+128] * inb[(c+128)*TT + t];
    a3 += wrow[c+192] * inb[(c+192)*TT + t];
  }
  float acc = (a0 + a1) + (a2 + a3);
  acc = fmaxf(acc, 0.f) + resid[(b*CHN + o)*TT + t];
  outb[si*CHN*TT*2 + (b*CHN + o)*TT + t] = acc;
}

// ---------------- banded attention (multi-slot) ----------------
__global__ void attn_kernel(const float* __restrict__ q, const float* __restrict__ k,
                            const float* __restrict__ v, const float* __restrict__ pos,
                            float* __restrict__ Aout_base, long long Astride,
                            float* __restrict__ out) {
  int t = blockIdx.x;
  int z = blockIdx.y;
  int si = z >> 1, b = z & 1;
  int lane = threadIdx.x;  // 64
  const float* qb = q + si*CHN*TT*2 + b * CHN * TT;
  const float* kb = k + si*CHN*TT*2 + b * CHN * TT;
  const float* vb = v + si*CHN*TT*2 + b * CHN * TT;
  float qc[4];
  #pragma unroll
  for (int i = 0; i < 4; ++i) qc[i] = qb[(lane + 64*i)*TT + t];

  float sc[17];
  #pragma unroll
  for (int j = 0; j < 17; ++j) {
    int s = t - 8 + j;
    bool inr = (s >= 0) && (s < TT);
    int ss = s < 0 ? 0 : (s > TT-1 ? TT-1 : s);
    float p = 0.f;
    #pragma unroll
    for (int i = 0; i < 4; ++i) p += qc[i] * kb[(lane + 64*i)*TT + ss];
    #pragma unroll
    for (int off = 32; off > 0; off >>= 1) p += __shfl_xor(p, off, 64);
    sc[j] = inr ? (p * 0.0625f + pos[t*TT + ss]) : -3.0e38f;
  }
  float m8 = sc[0];
  #pragma unroll
  for (int j = 1; j < 17; ++j) m8 = fmaxf(m8, sc[j]);
  float m4 = sc[4];
  #pragma unroll
  for (int j = 5; j < 13; ++j) m4 = fmaxf(m4, sc[j]);
  float e8[17], s8 = 0.f;
  #pragma unroll
  for (int j = 0; j < 17; ++j) { e8[j] = expf(sc[j] - m8); s8 += e8[j]; }
  float e4[9], s4 = 0.f;
  #pragma unroll
  for (int j = 0; j < 9; ++j) { e4[j] = expf(sc[4+j] - m4); s4 += e4[j]; }
  float i8 = 1.f / s8, i4 = 1.f / s4;
  float asum[17];
  #pragma unroll
  for (int j = 0; j < 17; ++j) {
    float a = e8[j] * i8;
    if (j >= 4 && j <= 12) a += e4[j-4] * i4;
    asum[j] = a;
  }
  #pragma unroll
  for (int i = 0; i < 4; ++i) {
    float acc = 0.f;
    #pragma unroll
    for (int j = 0; j < 17; ++j) {
      int s = t - 8 + j;
      int ss = s < 0 ? 0 : (s > TT-1 ? TT-1 : s);
      acc += asum[j] * vb[(lane + 64*i)*TT + ss];
    }
    out[si*CHN*TT*2 + (b*CHN + lane + 64*i)*TT + t] = acc;
  }
  __shared__ float lds_a[17];
  #pragma unroll
  for (int j = 0; j < 17; ++j) if (lane == j) lds_a[j] = asum[j];
  __syncthreads();
  float* Aout = Aout_base + (long long)si * Astride;
  for (int s = lane; s < TT; s += 64) {
    int j = s - (t - 8);
    float a = (j >= 0 && j < 17) ? lds_a[j] : 0.f;
    Aout[(b*TT + t)*TT + s] = a;
  }
}

// ---------------- start/end head ----------------
__global__ void head_kernel(const float* __restrict__ feat, const float* __restrict__ w,
                            const float* __restrict__ bias, float* __restrict__ outp) {
  int t = blockIdx.x * 64 + threadIdx.x;
  int b = blockIdx.y;
  if (t >= TT) return;
  float acc = bias[0];
  #pragma unroll 8
  for (int c = 0; c < CHN; ++c) acc += w[c] * feat[(b*CHN + c)*TT + t];
  outp[b*TT + t] = 1.f / (1.f + expf(-acc));
}

// ---------------- transpose cw1 into wT[r][c][o] ----------------
__global__ void w1t_kernel(const float* __restrict__ cw1, float* __restrict__ wT) {
  int idx = blockIdx.x * 256 + threadIdx.x;
  if (idx >= 128 * 4096) return;
  int o = idx >> 12;
  int cr = idx & 4095;
  int c = cr >> 4;
  int r = cr & 15;
  wT[(r*CHN + c)*128 + o] = cw1[idx];
}

// ---------------- g[b][r][x][o] = sum_c wT[r][c][o] * cfeat[b][c][x] ----------------
__global__ void g_kernel(const float* __restrict__ wT, const float* __restrict__ cf,
                         float* __restrict__ g) {
  int o = threadIdx.x;      // 128
  int xt = blockIdx.x;      // 50 tiles of 4
  int r = blockIdx.y;       // 16
  int b = blockIdx.z;       // 2
  float acc[4] = {0.f, 0.f, 0.f, 0.f};
  const float* wp = wT + r*CHN*128 + o;
  const float* cp = cf + b*CHN*TT + xt*4;
  for (int c = 0; c < CHN; ++c) {
    float wv = wp[c*128];
    #pragma unroll
    for (int j = 0; j < 4; ++j) acc[j] += wv * cp[c*TT + j];
  }
  float* gp = g + ((b*RESN + r)*TT + xt*4)*128 + o;
  #pragma unroll
  for (int j = 0; j < 4; ++j) gp[j*128] = acc[j];
}

// ---------------- fused align + 1x1 conv (cw1) + relu -> y1[b][o][d][t] ----------------
__global__ void align_conv1_kernel(const float* __restrict__ g, const float* __restrict__ cb1,
                                   float* __restrict__ y1) {
  int o = threadIdx.x;      // 128
  int t = blockIdx.x;       // 200
  int d = blockIdx.y;       // 64
  int b = blockIdx.z;
  bool vanch = (t + d) < TT;
  float clen = d + 1.0f;
  float xmin = vanch ? (t - clen * 0.5f) : 0.f;
  float xmax = vanch ? (t + d + clen * 0.5f) : 0.f;
  float acc = cb1[o];
  const float* gb = g + b*RESN*TT*128;
  #pragma unroll
  for (int r = 0; r < RESN; ++r) {
    float frac = (r + 0.5f) * (1.f/16.f);
    float p = xmin + (xmax - xmin) * frac;
    float x0 = floorf(p);
    float wf = p - x0;
    int x0i = (int)fminf(fmaxf(x0, 0.f), (float)(TT-1));
    int x1i = (int)fminf(fmaxf(x0 + 1.f, 0.f), (float)(TT-1));
    bool vp = (p >= -1.0f) && (p <= (float)TT);
    if (vp) {
      const float* gr = gb + r*TT*128;
      acc += (1.f - wf) * gr[x0i*128 + o] + wf * gr[x1i*128 + o];
    }
  }
  y1[((b*128 + o)*DUR + d)*TT + t] = fmaxf(acc, 0.f);
}

// ---------------- weight pack + bf16 hi/lo split for MFMA conv ----------------
// src [oc128][ic128][3][3] fp32 -> Apk[c][kd*3+kt][icc][hl][g4][oc128][p8] bf16
__global__ void wpack2_kernel(const float* __restrict__ cw2, const float* __restrict__ cw3,
                              short* __restrict__ Apk) {
  int idx = blockIdx.x*256 + threadIdx.x;
  if (idx >= 294912) return;
  int c = idx / 147456;
  int r = idx - c*147456;
  int oc = r / 1152;
  int r2 = r - oc*1152;
  int ic = r2 / 9;
  int kk = r2 - ic*9;
  float wv = (c ? cw3 : cw2)[r];
  unsigned h = rne_bf16(wv);
  float lf = wv - __uint_as_float(h << 16);
  unsigned lo = rne_bf16(lf);
  int icc = ic >> 5, g = (ic >> 3) & 3, p = ic & 7;
  size_t base = (size_t)c*294912 + (size_t)(kk*4 + icc)*8192 + (g*128 + oc)*8 + p;
  Apk[base] = (short)h;
  Apk[base + 4096] = (short)lo;
}

// ---------------- MFMA 3x3 conv: implicit GEMM, bf16 3-term split ----------------
// grid (4 t-tiles, 64 d, 2 b), block 256 = 4 waves (2m x 2n of 64oc x 32t).
// K-loop: 9 taps (kd,kt) x 4 ic-chunks of 32; one mfma_16x16x32 K-step per chunk.
__global__ __launch_bounds__(256, 2)
void conv_mfma_kernel(const float* __restrict__ in, const short* __restrict__ Apk,
                      const float* __restrict__ bias, float* __restrict__ outp) {
  __shared__ __align__(16) short Alds[8192];  // [hl][g4][oc128][8]
  __shared__ __align__(16) short Blds[4096];  // [hl][g4][t64][8]
  int tid = threadIdx.x, l = tid & 63, w = tid >> 6;
  int t0 = blockIdx.x * 64, d = blockIdx.y, b = blockIdx.z;
  int mh = w >> 1, nh = w & 1;
  const float* inb = in + (size_t)b*128*DUR*TT;
  float* outb = outp + (size_t)b*128*DUR*TT;

  f32x4 acc[4][2];
  #pragma unroll
  for (int mf = 0; mf < 4; ++mf)
    #pragma unroll
    for (int nf = 0; nf < 2; ++nf) acc[mf][nf] = (f32x4){0.f,0.f,0.f,0.f};

  int tq = tid & 15, icp = tid >> 4;   // B staging: coalesced t-reads, 2-way banks
  int gg = icp >> 2, uu = icp & 3;

  for (int kd = 0; kd < 3; ++kd) {
    int dd = d + kd - 1;
    bool dok = (unsigned)dd < (unsigned)DUR;
    for (int kt = 0; kt < 3; ++kt) {
      for (int icc = 0; icc < 4; ++icc) {
        __syncthreads();
        // stage A (16KB, fragment-ready layout, linear copy)
        const float4* asrc = (const float4*)(Apk + (size_t)((kd*3+kt)*4 + icc)*8192);
        float4* adst = (float4*)Alds;
        #pragma unroll
        for (int j = 0; j < 4; ++j) adst[tid*4 + j] = asrc[tid*4 + j];
        // stage B: read fp32, split to bf16 h/l, pack pairs
        {
          const float* rr0 = inb + ((size_t)(icc*32 + icp*2))*DUR*TT + (size_t)(dok ? dd : 0)*TT;
          const float* rr1 = rr0 + DUR*TT;
          unsigned* Bh = (unsigned*)Blds;
          unsigned* Bl = Bh + 1024;
          #pragma unroll
          for (int i = 0; i < 4; ++i) {
            int t = i*16 + tq;
            int ts = t0 + t + kt - 1;
            bool ok = dok && ((unsigned)ts < (unsigned)TT);
            float x0 = ok ? rr0[ts] : 0.f;
            float x1 = ok ? rr1[ts] : 0.f;
            unsigned h0 = rne_bf16(x0), h1 = rne_bf16(x1);
            float l0 = x0 - __uint_as_float(h0 << 16);
            float l1 = x1 - __uint_as_float(h1 << 16);
            unsigned lo0 = rne_bf16(l0), lo1 = rne_bf16(l1);
            Bh[(gg*64 + t)*4 + uu] = (h1 << 16) | h0;
            Bl[(gg*64 + t)*4 + uu] = (lo1 << 16) | lo0;
          }
        }
        __syncthreads();
        // fragments + mfma
        int g = l >> 4, r16 = l & 15;
        short8 ah[4], al[4], bh[2], bl[2];
        #pragma unroll
        for (int mf = 0; mf < 4; ++mf) {
          int oc = mh*64 + mf*16 + r16;
          ah[mf] = *(const short8*)&Alds[(g*128 + oc)*8];
          al[mf] = *(const short8*)&Alds[4096 + (g*128 + oc)*8];
        }
        #pragma unroll
        for (int nf = 0; nf < 2; ++nf) {
          int t = nh*32 + nf*16 + r16;
          bh[nf] = *(const short8*)&Blds[(g*64 + t)*8];
          bl[nf] = *(const short8*)&Blds[2048 + (g*64 + t)*8];
        }
        #pragma unroll
        for (int mf = 0; mf < 4; ++mf)
          #pragma unroll
          for (int nf = 0; nf < 2; ++nf) {
            acc[mf][nf] = __builtin_amdgcn_mfma_f32_16x16x32_bf16(ah[mf], bh[nf], acc[mf][nf], 0, 0, 0);
            acc[mf][nf] = __builtin_amdgcn_mfma_f32_16x16x32_bf16(ah[mf], bl[nf], acc[mf][nf], 0, 0, 0);
            acc[mf][nf] = __builtin_amdgcn_mfma_f32_16x16x32_bf16(al[mf], bh[nf], acc[mf][nf], 0, 0, 0);
          }
      }
    }
  }
  // epilogue: C row = (lane>>4)*4 + reg, col = lane&15 (verified m89)
  int g = l >> 4, r16 = l & 15;
  #pragma unroll
  for (int mf = 0; mf < 4; ++mf) {
    #pragma unroll
    for (int nf = 0; nf < 2; ++nf) {
      int t = t0 + nh*32 + nf*16 + r16;
      if (t < TT) {
        #pragma unroll
        for (int r = 0; r < 4; ++r) {
          int oc = mh*64 + mf*16 + g*4 + r;
          outb[(size_t)oc*DUR*TT + d*TT + t] = fmaxf(acc[mf][nf][r] + bias[oc], 0.f);
        }
      }
    }
  }
}

// ---------------- final 1x1 conv 128->2 + sigmoid -> conf ----------------
__global__ void conv4_kernel(const float* __restrict__ in, const float* __restrict__ w,
                             const float* __restrict__ bias, float* __restrict__ conf) {
  int t = blockIdx.x * 64 + threadIdx.x;
  int d = blockIdx.y;
  int b = blockIdx.z;
  if (t >= TT) return;
  float a0 = bias[0], a1 = bias[1];
  #pragma unroll 4
  for (int i = 0; i < 128; ++i) {
    float vv = in[((b*128 + i)*DUR + d)*TT + t];
    a0 += w[i] * vv;
    a1 += w[128 + i] * vv;
  }
  conf[((b*2 + 0)*DUR + d)*TT + t] = 1.f / (1.f + expf(-a0));
  conf[((b*2 + 1)*DUR + d)*TT + t] = 1.f / (1.f + expf(-a1));
}

extern "C" void kernel_launch(void* const* d_in, const int* in_sizes, int n_in,
                              void* d_out, int out_size, void* d_ws, size_t ws_size,
                              hipStream_t stream) {
  const float* x       = (const float*)d_in[0];
  const float* base_w  = (const float*)d_in[1];
  const float* base_b  = (const float*)d_in[2];
  const float* wq      = (const float*)d_in[3];
  const float* wk      = (const float*)d_in[4];
  const float* wv      = (const float*)d_in[5];
  const float* wo      = (const float*)d_in[6];
  const float* pos     = (const float*)d_in[7];
  const float* start_w = (const float*)d_in[8];
  const float* start_b = (const float*)d_in[9];
  const float* end_w   = (const float*)d_in[10];
  const float* end_b   = (const float*)d_in[11];
  const float* cw1     = (const float*)d_in[12];
  const float* cb1     = (const float*)d_in[13];
  const float* cw2     = (const float*)d_in[14];
  const float* cb2     = (const float*)d_in[15];
  const float* cw3     = (const float*)d_in[16];
  const float* cb3     = (const float*)d_in[17];
  const float* cw4     = (const float*)d_in[18];
  const float* cb4     = (const float*)d_in[19];

  float* out = (float*)d_out;
  float* conf_out  = out;
  float* start_out = out + 51200;
  float* end_out   = out + 51600;
  float* As_out    = out + 52000;    // Ae, Ap follow at stride 80000

  float* ws = (float*)d_ws;
  float* h      = ws;                 // 102400
  float* basef  = ws + 102400;        // 102400
  float* feats3 = ws + 204800;        // 307200
  float* wT     = ws + 512000;        // 524288 (Apk overlays after g_kernel: 294912)
  float* gbuf   = ws + 1036288;       // 819200
  float* y1     = ws + 1855488;       // 3276800
  float* y2     = ws + 5132288;       // 3276800
  float* qb3    = y1;                 // overlays in y1 (dead before align writes y1)
  float* kb3    = y1 + 307200;
  float* vb3    = y1 + 614400;
  float* ao3    = y1 + 921600;
  float* partial= y1 + 1228800;
  float* A_scr  = y2;                 // overlay in y2 (write-only, dead before conv2)
  short* Apk    = (short*)wT;         // 589824 shorts = 294912 floats <= 524288

  dim3 b64(64);
  dim3 b256(256);

  base_conv_part<<<dim3(4, 16, 16), b256, 0, stream>>>(x, base_w, partial);
  base_reduce<<<dim3(400), b256, 0, stream>>>(partial, base_b, h);

  qkv_kernel<<<dim3(4, 256, 2), b64, 0, stream>>>(wq, wk, wv, 0, h, qb3, kb3, vb3);
  attn_kernel<<<dim3(200, 2), b64, 0, stream>>>(qb3, kb3, vb3, pos, A_scr, 0, ao3);
  proj_kernel<<<dim3(4, 256, 2), b64, 0, stream>>>(wo, 0, ao3, h, basef);

  qkv_kernel<<<dim3(4, 256, 6), b64, 0, stream>>>(wq, wk, wv, 1, basef, qb3, kb3, vb3);
  attn_kernel<<<dim3(200, 6), b64, 0, stream>>>(qb3, kb3, vb3, pos, As_out, 80000, ao3);
  proj_kernel<<<dim3(4, 256, 6), b64, 0, stream>>>(wo, 1, ao3, basef, feats3);

  head_kernel<<<dim3(4, 2), b64, 0, stream>>>(feats3, start_w, start_b, start_out);
  head_kernel<<<dim3(4, 2), b64, 0, stream>>>(feats3 + 102400, end_w, end_b, end_out);

  const float* cfeat = feats3 + 204800;
  w1t_kernel<<<dim3(2048), b256, 0, stream>>>(cw1, wT);
  g_kernel<<<dim3(50, 16, 2), dim3(128), 0, stream>>>(wT, cfeat, gbuf);
  // wT (fp32) dead after g_kernel; pack bf16-split conv weights into its region
  wpack2_kernel<<<dim3(1152), b256, 0, stream>>>(cw2, cw3, Apk);
  align_conv1_kernel<<<dim3(200, 64, 2), dim3(128), 0, stream>>>(gbuf, cb1, y1);

  conv_mfma_kernel<<<dim3(4, 64, 2), b256, 0, stream>>>(y1, Apk, cb2, y2);
  conv_mfma_kernel<<<dim3(4, 64, 2), b256, 0, stream>>>(y2, Apk + 294912, cb3, y1);
  conv4_kernel<<<dim3(4, 64, 2), b64, 0, stream>>>(y1, cw4, cb4, conf_out);
}